// Round 3
// baseline (3359.189 us; speedup 1.0000x reference)
//
#include <hip/hip_runtime.h>
#include <cmath>

// ---------------------------------------------------------------------------
// Decoder_1898375544952: STGCN decoder (CSR gather + tiled-GEMM combine)
//   h0 = x @ W_lin + b_lin                         [N,16]
//   h3 = relu(h0 @ Ws3 + mean_agg(h0) @ Wn3 + b3)  [N,32]
//   h2 = relu(h3 @ Ws2 + mean_agg(h3) @ Wn2 + b2)  [N,64]
//   out= sigm(h2 @ Ws1 + mean_agg(h2) @ Wn1 + b1)  [N,128]
//
// R1: fp32 atomic scatter = 2 GB write-through -> CSR gather (R2, 4.7x).
// R2: combine kernels LDS-BW bound (8.6 GB LDS, 153 us) -> R3: combine as
// register-blocked tiled GEMM over [h | agg/deg] @ [Ws; Wn]; gather folds
// the deg division so agg buffers hold agg/deg.
// ---------------------------------------------------------------------------

__global__ void hist_kernel(const int* __restrict__ dst, int* __restrict__ cnt, int E) {
    int i = blockIdx.x * blockDim.x + threadIdx.x;
    if (i < E) atomicAdd(&cnt[dst[i]], 1);
}

// Block-level exclusive scan of cnt -> row_ptr (partial), block sums -> bsum.
// Requires N % 256 == 0.
__global__ void scan1_kernel(const int* __restrict__ cnt, int* __restrict__ row_ptr,
                             int* __restrict__ bsum) {
    __shared__ int s[256];
    int i = blockIdx.x * 256 + threadIdx.x;
    int v = cnt[i];
    s[threadIdx.x] = v;
    __syncthreads();
    for (int off = 1; off < 256; off <<= 1) {
        int t = (threadIdx.x >= off) ? s[threadIdx.x - off] : 0;
        __syncthreads();
        s[threadIdx.x] += t;
        __syncthreads();
    }
    row_ptr[i] = s[threadIdx.x] - v;   // exclusive within block
    if (threadIdx.x == 255) bsum[blockIdx.x] = s[255];
}

// Exclusive scan of bsum[NB] in place, single block of NB threads (NB<=1024).
__global__ void scan2_kernel(int* __restrict__ bsum, int NB) {
    extern __shared__ int s2[];
    int v = (threadIdx.x < NB) ? bsum[threadIdx.x] : 0;
    s2[threadIdx.x] = v;
    __syncthreads();
    for (int off = 1; off < NB; off <<= 1) {
        int t = (threadIdx.x >= off) ? s2[threadIdx.x - off] : 0;
        __syncthreads();
        s2[threadIdx.x] += t;
        __syncthreads();
    }
    if (threadIdx.x < NB) bsum[threadIdx.x] = s2[threadIdx.x] - v;
}

__global__ void scan3_kernel(int* __restrict__ row_ptr, const int* __restrict__ bsum,
                             int N, int E) {
    int i = blockIdx.x * 256 + threadIdx.x;
    row_ptr[i] += bsum[blockIdx.x];
    if (i == 0) row_ptr[N] = E;
}

__global__ void fill_kernel(const int* __restrict__ src, const int* __restrict__ dst,
                            const int* __restrict__ row_ptr, int* __restrict__ cursor,
                            int* __restrict__ csr_src, int E) {
    int i = blockIdx.x * blockDim.x + threadIdx.x;
    if (i >= E) return;
    int d = dst[i];
    int p = atomicAdd(&cursor[d], 1);
    csr_src[row_ptr[d] + p] = src[i];
}

// h0 = x @ W (16x16) + b
__global__ void lin16_kernel(const float* __restrict__ x, const float* __restrict__ W,
                             const float* __restrict__ b, float* __restrict__ h, int N) {
    __shared__ float sW[256];
    __shared__ float sb[16];
    sW[threadIdx.x] = W[threadIdx.x];          // blockDim.x == 256
    if (threadIdx.x < 16) sb[threadIdx.x] = b[threadIdx.x];
    __syncthreads();
    int n = blockIdx.x * blockDim.x + threadIdx.x;
    if (n >= N) return;
    const float4* xr = (const float4*)(x + (size_t)n * 16);
    float4 x0 = xr[0], x1 = xr[1], x2 = xr[2], x3 = xr[3];
    float xi[16] = {x0.x, x0.y, x0.z, x0.w, x1.x, x1.y, x1.z, x1.w,
                    x2.x, x2.y, x2.z, x2.w, x3.x, x3.y, x3.z, x3.w};
    float o[16];
#pragma unroll
    for (int j = 0; j < 16; j++) o[j] = sb[j];
#pragma unroll
    for (int k = 0; k < 16; k++) {
        float xv = xi[k];
#pragma unroll
        for (int j = 0; j < 16; j++) o[j] += xv * sW[k * 16 + j];
    }
    float4* hr = (float4*)(h + (size_t)n * 16);
    hr[0] = make_float4(o[0], o[1], o[2], o[3]);
    hr[1] = make_float4(o[4], o[5], o[6], o[7]);
    hr[2] = make_float4(o[8], o[9], o[10], o[11]);
    hr[3] = make_float4(o[12], o[13], o[14], o[15]);
}

// agg[n][g*4..] = (1/max(deg,1)) * sum over CSR neighbors of h[src][g*4..]
template <int C>
__global__ void gather_kernel(const int* __restrict__ row_ptr, const int* __restrict__ csr_src,
                              const float* __restrict__ h, float* __restrict__ agg, int N) {
    constexpr int GP = C / 4;
    int t = blockIdx.x * blockDim.x + threadIdx.x;
    int total = N * GP;
    if (t >= total) return;
    int n = t / GP;
    int g = t - n * GP;
    int beg = row_ptr[n];
    int end = row_ptr[n + 1];
    float4 s = make_float4(0.f, 0.f, 0.f, 0.f);
    for (int j = beg; j < end; ++j) {
        int sn = csr_src[j];
        float4 v = *(const float4*)(h + (size_t)sn * C + g * 4);
        s.x += v.x; s.y += v.y; s.z += v.z; s.w += v.w;
    }
    float inv = 1.0f / fmaxf((float)(end - beg), 1.0f);
    s.x *= inv; s.y *= inv; s.z *= inv; s.w *= inv;
    *(float4*)(agg + (size_t)n * C + g * 4) = s;
}

// Tiled GEMM: out[n][j] = act( sum_k h[n][k]*Ws[k][j] + a[n][k]*Wn[k][j] + b[j] )
// Logical A = [h | a] (K = 2*CI), B = [Ws; Wn].
// Block: 256 threads, BM rows x NOUT cols, thread tile TM x TN, BK = min(32,CI).
// ACT: 0 = relu, 1 = sigmoid
template <int CI, int NOUT, int TM, int TN, int ACT>
__global__ __launch_bounds__(256) void gemm_kernel(
    const float* __restrict__ hbuf,   // [N][CI]
    const float* __restrict__ abuf,   // [N][CI]  (already divided by deg)
    const float* __restrict__ Ws,     // [CI][NOUT]
    const float* __restrict__ Wn,     // [CI][NOUT]
    const float* __restrict__ bias,   // [NOUT]
    float* __restrict__ out, int N)
{
    constexpr int K  = 2 * CI;
    constexpr int BK = (CI < 32) ? CI : 32;
    constexpr int TX = NOUT / TN;          // threads along cols
    constexpr int TY = 256 / TX;           // threads along rows
    constexpr int BM = TY * TM;            // rows per block
    constexpr int LDA = BM + 4;            // pad keeps 16B alignment + fewer conflicts
    __shared__ float As[BK][LDA];          // k-major, transposed
    __shared__ float Bs[BK][NOUT];

    const int tid  = threadIdx.x;
    const int tx   = tid % TX;
    const int ty   = tid / TX;
    const int row0 = blockIdx.x * BM;
    const int m0   = ty * TM;
    const int j0   = tx * TN;

    float acc[TM][TN];
#pragma unroll
    for (int r = 0; r < TM; r++)
#pragma unroll
        for (int j = 0; j < TN; j++) acc[r][j] = 0.0f;

#pragma unroll
    for (int k0 = 0; k0 < K; k0 += BK) {
        const bool  hhalf = (k0 < CI);
        const float* Asrc = hhalf ? hbuf : abuf;
        const float* Bsrc = hhalf ? Ws : Wn;
        const int    ks   = hhalf ? k0 : (k0 - CI);

        // stage A: BM rows x BK cols -> As[k][m] (transposed)
        for (int idx = tid; idx < BM * (BK / 4); idx += 256) {
            int m  = idx / (BK / 4);
            int kq = idx % (BK / 4);
            float4 v = *(const float4*)(Asrc + (size_t)(row0 + m) * CI + ks + kq * 4);
            As[kq * 4 + 0][m] = v.x;
            As[kq * 4 + 1][m] = v.y;
            As[kq * 4 + 2][m] = v.z;
            As[kq * 4 + 3][m] = v.w;
        }
        // stage B: BK x NOUT (already row-major)
        for (int idx = tid; idx < BK * (NOUT / 4); idx += 256) {
            int kk = idx / (NOUT / 4);
            int jq = idx % (NOUT / 4);
            *(float4*)&Bs[kk][jq * 4] =
                *(const float4*)(Bsrc + (size_t)(ks + kk) * NOUT + jq * 4);
        }
        __syncthreads();

#pragma unroll
        for (int k = 0; k < BK; k++) {
            float a[TM], b[TN];
#pragma unroll
            for (int i = 0; i < TM; i += 4)
                *(float4*)&a[i] = *(const float4*)&As[k][m0 + i];
#pragma unroll
            for (int i = 0; i < TN; i += 4)
                *(float4*)&b[i] = *(const float4*)&Bs[k][j0 + i];
#pragma unroll
            for (int r = 0; r < TM; r++)
#pragma unroll
                for (int j = 0; j < TN; j++)
                    acc[r][j] += a[r] * b[j];
        }
        __syncthreads();
    }

    // epilogue
    float bv[TN];
#pragma unroll
    for (int i = 0; i < TN; i += 4)
        *(float4*)&bv[i] = *(const float4*)(bias + j0 + i);

#pragma unroll
    for (int r = 0; r < TM; r++) {
        size_t nrow = (size_t)(row0 + m0 + r);
#pragma unroll
        for (int j = 0; j < TN; j += 4) {
            float4 v;
            v.x = acc[r][j + 0] + bv[j + 0];
            v.y = acc[r][j + 1] + bv[j + 1];
            v.z = acc[r][j + 2] + bv[j + 2];
            v.w = acc[r][j + 3] + bv[j + 3];
            if (ACT == 0) {
                v.x = fmaxf(v.x, 0.0f); v.y = fmaxf(v.y, 0.0f);
                v.z = fmaxf(v.z, 0.0f); v.w = fmaxf(v.w, 0.0f);
            } else {
                v.x = 1.0f / (1.0f + __expf(-v.x));
                v.y = 1.0f / (1.0f + __expf(-v.y));
                v.z = 1.0f / (1.0f + __expf(-v.z));
                v.w = 1.0f / (1.0f + __expf(-v.w));
            }
            *(float4*)(out + nrow * NOUT + j0 + j) = v;
        }
    }
}

extern "C" void kernel_launch(void* const* d_in, const int* in_sizes, int n_in,
                              void* d_out, int out_size, void* d_ws, size_t ws_size,
                              hipStream_t stream) {
    const float* x     = (const float*)d_in[0];
    const int*   ei    = (const int*)d_in[1];
    // d_in[2]: batch (unused)
    const float* W_lin = (const float*)d_in[3];
    const float* b_lin = (const float*)d_in[4];
    const float* Ws3   = (const float*)d_in[5];
    const float* Wn3   = (const float*)d_in[6];
    const float* b3    = (const float*)d_in[7];
    const float* Ws2   = (const float*)d_in[8];
    const float* Wn2   = (const float*)d_in[9];
    const float* b2    = (const float*)d_in[10];
    const float* Ws1   = (const float*)d_in[11];
    const float* Wn1   = (const float*)d_in[12];
    const float* b1    = (const float*)d_in[13];
    float* out = (float*)d_out;

    const int N = in_sizes[0] / 16;
    const int E = in_sizes[1] / 2;
    const int* src = ei;
    const int* dst = ei + E;
    const int NB = (N + 255) / 256;   // scan blocks (512 for N=131072)

    // Workspace (ints/floats, 4 B each). Peak = 76.55 MB (same as R2, proven fit).
    //   row_ptr : [0, N+1)
    //   cnt     : [N+1, 2N+1)      (doubles as fill cursor)
    //   bsum    : [2N+1, 2N+1+NB)
    //   csr_src : [A, A+E)
    //   regionA (64N floats at P0): h0 [0,16N) agg16 [16N,32N); later h2 [0,64N)
    //   regionB (64N floats at P1): h3 [0,32N) agg32 [32N,64N); later agg64 [0,64N)
    int* wsi = (int*)d_ws;
    int* row_ptr = wsi;
    int* cnt     = wsi + (N + 1);
    int* bsum    = wsi + (2 * N + 1);
    size_t A = (size_t)(2 * N + 1 + NB + 3) & ~(size_t)3;
    int* csr_src = wsi + A;
    size_t P0 = (A + (size_t)E + 3) & ~(size_t)3;
    float* regA = (float*)(wsi + P0);
    float* regB = regA + (size_t)64 * N;

    float* h0    = regA;
    float* agg16 = regA + (size_t)16 * N;
    float* h2    = regA;                      // after h0/agg16 dead
    float* h3    = regB;
    float* agg32 = regB + (size_t)32 * N;
    float* agg64 = regB;                      // after h3/agg32 dead

    const int BLK = 256;

    // ---- CSR build (int atomics only) ----
    hipMemsetAsync(cnt, 0, (size_t)N * 4, stream);
    hist_kernel<<<(E + BLK - 1) / BLK, BLK, 0, stream>>>(dst, cnt, E);
    scan1_kernel<<<NB, 256, 0, stream>>>(cnt, row_ptr, bsum);
    scan2_kernel<<<1, NB, NB * sizeof(int), stream>>>(bsum, NB);
    scan3_kernel<<<NB, 256, 0, stream>>>(row_ptr, bsum, N, E);
    hipMemsetAsync(cnt, 0, (size_t)N * 4, stream);   // cursor = 0
    fill_kernel<<<(E + BLK - 1) / BLK, BLK, 0, stream>>>(src, dst, row_ptr, cnt, csr_src, E);

    // ---- h0 = x @ W_lin + b_lin ----
    lin16_kernel<<<(N + BLK - 1) / BLK, BLK, 0, stream>>>(x, W_lin, b_lin, h0, N);

    // ---- block3: 16 -> 32, relu ----
    gather_kernel<16><<<((size_t)N * 4 + BLK - 1) / BLK, BLK, 0, stream>>>(row_ptr, csr_src, h0, agg16, N);
    gemm_kernel<16, 32, 4, 4, 0><<<N / 128, 256, 0, stream>>>(h0, agg16, Ws3, Wn3, b3, h3, N);

    // ---- block2: 32 -> 64, relu ----
    gather_kernel<32><<<((size_t)N * 8 + BLK - 1) / BLK, BLK, 0, stream>>>(row_ptr, csr_src, h3, agg32, N);
    gemm_kernel<32, 64, 8, 4, 0><<<N / 128, 256, 0, stream>>>(h3, agg32, Ws2, Wn2, b2, h2, N);

    // ---- block1: 64 -> 128, sigmoid -> d_out ----
    gather_kernel<64><<<((size_t)N * 16 + BLK - 1) / BLK, BLK, 0, stream>>>(row_ptr, csr_src, h2, agg64, N);
    gemm_kernel<64, 128, 8, 8, 1><<<N / 128, 256, 0, stream>>>(h2, agg64, Ws1, Wn1, b1, out, N);
}

// Round 4
// 653.813 us; speedup vs baseline: 5.1378x; 5.1378x over previous
//
#include <hip/hip_runtime.h>
#include <cmath>

// ---------------------------------------------------------------------------
// Decoder_1898375544952: STGCN decoder (CSR gather + register-blocked GEMM)
//   h0 = x @ W_lin + b_lin                         [N,16]
//   h3 = relu(h0 @ Ws3 + mean_agg(h0) @ Wn3 + b3)  [N,32]
//   h2 = relu(h3 @ Ws2 + mean_agg(h3) @ Wn2 + b2)  [N,64]
//   out= sigm(h2 @ Ws1 + mean_agg(h2) @ Wn1 + b1)  [N,128]
//
// R1: fp32 atomic scatter = 2 GB write-through -> CSR gather (R2, 4.7x).
// R2: combine LDS-BW bound (no reg blocking).
// R3: 8x8-tile GEMM spilled (VGPR=256, FETCH 5.8 GB scratch traffic) -> R4:
//   TMx4 tile (<=32 acc regs), m-major A staging (no transpose), interleaved
//   row ownership (m = ty + TY*r) for conflict-free column reads,
//   unroll-1 outer chunk loop to keep liveness bounded.
// ---------------------------------------------------------------------------

__global__ void hist_kernel(const int* __restrict__ dst, int* __restrict__ cnt, int E) {
    int i = blockIdx.x * blockDim.x + threadIdx.x;
    if (i < E) atomicAdd(&cnt[dst[i]], 1);
}

__global__ void scan1_kernel(const int* __restrict__ cnt, int* __restrict__ row_ptr,
                             int* __restrict__ bsum) {
    __shared__ int s[256];
    int i = blockIdx.x * 256 + threadIdx.x;
    int v = cnt[i];
    s[threadIdx.x] = v;
    __syncthreads();
    for (int off = 1; off < 256; off <<= 1) {
        int t = (threadIdx.x >= off) ? s[threadIdx.x - off] : 0;
        __syncthreads();
        s[threadIdx.x] += t;
        __syncthreads();
    }
    row_ptr[i] = s[threadIdx.x] - v;   // exclusive within block
    if (threadIdx.x == 255) bsum[blockIdx.x] = s[255];
}

__global__ void scan2_kernel(int* __restrict__ bsum, int NB) {
    extern __shared__ int s2[];
    int v = (threadIdx.x < NB) ? bsum[threadIdx.x] : 0;
    s2[threadIdx.x] = v;
    __syncthreads();
    for (int off = 1; off < NB; off <<= 1) {
        int t = (threadIdx.x >= off) ? s2[threadIdx.x - off] : 0;
        __syncthreads();
        s2[threadIdx.x] += t;
        __syncthreads();
    }
    if (threadIdx.x < NB) bsum[threadIdx.x] = s2[threadIdx.x] - v;
}

__global__ void scan3_kernel(int* __restrict__ row_ptr, const int* __restrict__ bsum,
                             int N, int E) {
    int i = blockIdx.x * 256 + threadIdx.x;
    row_ptr[i] += bsum[blockIdx.x];
    if (i == 0) row_ptr[N] = E;
}

__global__ void fill_kernel(const int* __restrict__ src, const int* __restrict__ dst,
                            const int* __restrict__ row_ptr, int* __restrict__ cursor,
                            int* __restrict__ csr_src, int E) {
    int i = blockIdx.x * blockDim.x + threadIdx.x;
    if (i >= E) return;
    int d = dst[i];
    int p = atomicAdd(&cursor[d], 1);
    csr_src[row_ptr[d] + p] = src[i];
}

__global__ void lin16_kernel(const float* __restrict__ x, const float* __restrict__ W,
                             const float* __restrict__ b, float* __restrict__ h, int N) {
    __shared__ float sW[256];
    __shared__ float sb[16];
    sW[threadIdx.x] = W[threadIdx.x];          // blockDim.x == 256
    if (threadIdx.x < 16) sb[threadIdx.x] = b[threadIdx.x];
    __syncthreads();
    int n = blockIdx.x * blockDim.x + threadIdx.x;
    if (n >= N) return;
    const float4* xr = (const float4*)(x + (size_t)n * 16);
    float4 x0 = xr[0], x1 = xr[1], x2 = xr[2], x3 = xr[3];
    float xi[16] = {x0.x, x0.y, x0.z, x0.w, x1.x, x1.y, x1.z, x1.w,
                    x2.x, x2.y, x2.z, x2.w, x3.x, x3.y, x3.z, x3.w};
    float o[16];
#pragma unroll
    for (int j = 0; j < 16; j++) o[j] = sb[j];
#pragma unroll
    for (int k = 0; k < 16; k++) {
        float xv = xi[k];
#pragma unroll
        for (int j = 0; j < 16; j++) o[j] += xv * sW[k * 16 + j];
    }
    float4* hr = (float4*)(h + (size_t)n * 16);
    hr[0] = make_float4(o[0], o[1], o[2], o[3]);
    hr[1] = make_float4(o[4], o[5], o[6], o[7]);
    hr[2] = make_float4(o[8], o[9], o[10], o[11]);
    hr[3] = make_float4(o[12], o[13], o[14], o[15]);
}

// agg[n][g*4..] = (1/max(deg,1)) * sum over CSR neighbors of h[src][g*4..]
template <int C>
__global__ void gather_kernel(const int* __restrict__ row_ptr, const int* __restrict__ csr_src,
                              const float* __restrict__ h, float* __restrict__ agg, int N) {
    constexpr int GP = C / 4;
    int t = blockIdx.x * blockDim.x + threadIdx.x;
    int total = N * GP;
    if (t >= total) return;
    int n = t / GP;
    int g = t - n * GP;
    int beg = row_ptr[n];
    int end = row_ptr[n + 1];
    float4 s = make_float4(0.f, 0.f, 0.f, 0.f);
    for (int j = beg; j < end; ++j) {
        int sn = csr_src[j];
        float4 v = *(const float4*)(h + (size_t)sn * C + g * 4);
        s.x += v.x; s.y += v.y; s.z += v.z; s.w += v.w;
    }
    float inv = 1.0f / fmaxf((float)(end - beg), 1.0f);
    s.x *= inv; s.y *= inv; s.z *= inv; s.w *= inv;
    *(float4*)(agg + (size_t)n * C + g * 4) = s;
}

// Register-blocked GEMM: out = act([h | a] @ [Ws; Wn] + b). 256 threads.
// Thread owns TM interleaved rows (m = ty + TY*r) x TN=4 cols; As m-major.
// ACT: 0 = relu, 1 = sigmoid
template <int CI, int NOUT, int TM, int TN, int ACT>
__global__ __launch_bounds__(256) void gemm_kernel(
    const float* __restrict__ hbuf,   // [N][CI]
    const float* __restrict__ abuf,   // [N][CI]  (already divided by deg)
    const float* __restrict__ Ws,     // [CI][NOUT]
    const float* __restrict__ Wn,     // [CI][NOUT]
    const float* __restrict__ bias,   // [NOUT]
    float* __restrict__ out, int N)
{
    constexpr int K   = 2 * CI;
    constexpr int BK  = (CI < 32) ? CI : 32;   // each chunk entirely in h- or a-half
    constexpr int KQ  = BK / 4;
    constexpr int TX  = NOUT / TN;
    constexpr int TY  = 256 / TX;
    constexpr int BM  = TY * TM;
    constexpr int LDA = BK + 4;                // multiple of 4 -> float4-aligned rows
    __shared__ float As[BM][LDA];
    __shared__ float Bs[BK][NOUT];

    const int tid  = threadIdx.x;
    const int tx   = tid % TX;
    const int ty   = tid / TX;
    const int row0 = blockIdx.x * BM;
    const int j0   = tx * TN;

    float acc[TM][TN];
#pragma unroll
    for (int r = 0; r < TM; r++)
#pragma unroll
        for (int j = 0; j < TN; j++) acc[r][j] = 0.0f;

#pragma unroll 1
    for (int k0 = 0; k0 < K; k0 += BK) {
        const float* Asrc;
        const float* Bsrc;
        int ks;
        if (k0 < CI) { Asrc = hbuf; Bsrc = Ws; ks = k0; }
        else         { Asrc = abuf; Bsrc = Wn; ks = k0 - CI; }

        for (int idx = tid; idx < BM * KQ; idx += 256) {
            int m  = idx / KQ;
            int kq = idx - m * KQ;
            float4 v = *(const float4*)(Asrc + (size_t)(row0 + m) * CI + ks + kq * 4);
            *(float4*)&As[m][kq * 4] = v;
        }
        for (int idx = tid; idx < BK * (NOUT / 4); idx += 256) {
            int kk = idx / (NOUT / 4);
            int jq = idx - kk * (NOUT / 4);
            *(float4*)&Bs[kk][jq * 4] =
                *(const float4*)(Bsrc + (size_t)(ks + kk) * NOUT + jq * 4);
        }
        __syncthreads();

#pragma unroll 8
        for (int k = 0; k < BK; k++) {
            float4 bv = *(const float4*)&Bs[k][j0];
            float a[TM];
#pragma unroll
            for (int r = 0; r < TM; r++) a[r] = As[ty + TY * r][k];
#pragma unroll
            for (int r = 0; r < TM; r++) {
                acc[r][0] += a[r] * bv.x;
                acc[r][1] += a[r] * bv.y;
                acc[r][2] += a[r] * bv.z;
                acc[r][3] += a[r] * bv.w;
            }
        }
        __syncthreads();
    }

    float4 bb = *(const float4*)(bias + j0);
#pragma unroll
    for (int r = 0; r < TM; r++) {
        size_t nrow = (size_t)(row0 + ty + TY * r);
        float4 v;
        v.x = acc[r][0] + bb.x;
        v.y = acc[r][1] + bb.y;
        v.z = acc[r][2] + bb.z;
        v.w = acc[r][3] + bb.w;
        if (ACT == 0) {
            v.x = fmaxf(v.x, 0.0f); v.y = fmaxf(v.y, 0.0f);
            v.z = fmaxf(v.z, 0.0f); v.w = fmaxf(v.w, 0.0f);
        } else {
            v.x = 1.0f / (1.0f + __expf(-v.x));
            v.y = 1.0f / (1.0f + __expf(-v.y));
            v.z = 1.0f / (1.0f + __expf(-v.z));
            v.w = 1.0f / (1.0f + __expf(-v.w));
        }
        *(float4*)(out + nrow * NOUT + j0) = v;
    }
}

extern "C" void kernel_launch(void* const* d_in, const int* in_sizes, int n_in,
                              void* d_out, int out_size, void* d_ws, size_t ws_size,
                              hipStream_t stream) {
    const float* x     = (const float*)d_in[0];
    const int*   ei    = (const int*)d_in[1];
    const float* W_lin = (const float*)d_in[3];
    const float* b_lin = (const float*)d_in[4];
    const float* Ws3   = (const float*)d_in[5];
    const float* Wn3   = (const float*)d_in[6];
    const float* b3    = (const float*)d_in[7];
    const float* Ws2   = (const float*)d_in[8];
    const float* Wn2   = (const float*)d_in[9];
    const float* b2    = (const float*)d_in[10];
    const float* Ws1   = (const float*)d_in[11];
    const float* Wn1   = (const float*)d_in[12];
    const float* b1    = (const float*)d_in[13];
    float* out = (float*)d_out;

    const int N = in_sizes[0] / 16;
    const int E = in_sizes[1] / 2;
    const int* src = ei;
    const int* dst = ei + E;
    const int NB = (N + 255) / 256;

    int* wsi = (int*)d_ws;
    int* row_ptr = wsi;
    int* cnt     = wsi + (N + 1);
    int* bsum    = wsi + (2 * N + 1);
    size_t A = (size_t)(2 * N + 1 + NB + 3) & ~(size_t)3;
    int* csr_src = wsi + A;
    size_t P0 = (A + (size_t)E + 3) & ~(size_t)3;
    float* regA = (float*)(wsi + P0);
    float* regB = regA + (size_t)64 * N;

    float* h0    = regA;
    float* agg16 = regA + (size_t)16 * N;
    float* h2    = regA;                      // after h0/agg16 dead
    float* h3    = regB;
    float* agg32 = regB + (size_t)32 * N;
    float* agg64 = regB;                      // after h3/agg32 dead

    const int BLK = 256;

    // ---- CSR build (int atomics only) ----
    hipMemsetAsync(cnt, 0, (size_t)N * 4, stream);
    hist_kernel<<<(E + BLK - 1) / BLK, BLK, 0, stream>>>(dst, cnt, E);
    scan1_kernel<<<NB, 256, 0, stream>>>(cnt, row_ptr, bsum);
    scan2_kernel<<<1, NB, NB * sizeof(int), stream>>>(bsum, NB);
    scan3_kernel<<<NB, 256, 0, stream>>>(row_ptr, bsum, N, E);
    hipMemsetAsync(cnt, 0, (size_t)N * 4, stream);   // cursor = 0
    fill_kernel<<<(E + BLK - 1) / BLK, BLK, 0, stream>>>(src, dst, row_ptr, cnt, csr_src, E);

    // ---- h0 = x @ W_lin + b_lin ----
    lin16_kernel<<<(N + BLK - 1) / BLK, BLK, 0, stream>>>(x, W_lin, b_lin, h0, N);

    // ---- block3: 16 -> 32, relu ----  (BM = 128)
    gather_kernel<16><<<((size_t)N * 4 + BLK - 1) / BLK, BLK, 0, stream>>>(row_ptr, csr_src, h0, agg16, N);
    gemm_kernel<16, 32, 4, 4, 0><<<N / 128, 256, 0, stream>>>(h0, agg16, Ws3, Wn3, b3, h3, N);

    // ---- block2: 32 -> 64, relu ----  (BM = 128)
    gather_kernel<32><<<((size_t)N * 8 + BLK - 1) / BLK, BLK, 0, stream>>>(row_ptr, csr_src, h3, agg32, N);
    gemm_kernel<32, 64, 8, 4, 0><<<N / 128, 256, 0, stream>>>(h3, agg32, Ws2, Wn2, b2, h2, N);

    // ---- block1: 64 -> 128, sigmoid -> d_out ----  (BM = 64)
    gather_kernel<64><<<((size_t)N * 16 + BLK - 1) / BLK, BLK, 0, stream>>>(row_ptr, csr_src, h2, agg64, N);
    gemm_kernel<64, 128, 8, 4, 1><<<N / 64, 256, 0, stream>>>(h2, agg64, Ws1, Wn1, b1, out, N);
}

// Round 5
// 547.994 us; speedup vs baseline: 6.1300x; 1.1931x over previous
//
#include <hip/hip_runtime.h>
#include <cmath>

// ---------------------------------------------------------------------------
// Decoder_1898375544952: STGCN decoder (CSR gather + register-blocked GEMM)
//   h0 = x @ W_lin + b_lin                         [N,16]
//   h3 = relu(h0 @ Ws3 + mean_agg(h0) @ Wn3 + b3)  [N,32]
//   h2 = relu(h3 @ Ws2 + mean_agg(h3) @ Wn2 + b2)  [N,64]
//   out= sigm(h2 @ Ws1 + mean_agg(h2) @ Wn1 + b1)  [N,128]
//
// R1: fp32 atomic scatter = 2 GB HBM write-through -> CSR gather (4.7x).
// R2: combine kernels LDS-BW bound -> register-blocked GEMM.
// R3: over-unrolled GEMM spilled (VGPR=256) -> unroll-1 chunks, TMx4 tiles.
// R4: fill_kernel = atomic+dependent-random-store, 68 B HBM/edge, 153 us ->
// R5: rank computed in hist (atomicAdd return value, coalesced store);
//     fill is now atomic-free (one random 4B store per edge); cursor +
//     second memset eliminated. rank aliases regB (dead before h3 written).
// ---------------------------------------------------------------------------

__global__ void hist_rank_kernel(const int* __restrict__ dst, int* __restrict__ cnt,
                                 int* __restrict__ rank, int E) {
    int i = blockIdx.x * blockDim.x + threadIdx.x;
    if (i >= E) return;
    rank[i] = atomicAdd(&cnt[dst[i]], 1);
}

// Block-level exclusive scan of cnt -> row_ptr (partial), block sums -> bsum.
// Requires N % 256 == 0.
__global__ void scan1_kernel(const int* __restrict__ cnt, int* __restrict__ row_ptr,
                             int* __restrict__ bsum) {
    __shared__ int s[256];
    int i = blockIdx.x * 256 + threadIdx.x;
    int v = cnt[i];
    s[threadIdx.x] = v;
    __syncthreads();
    for (int off = 1; off < 256; off <<= 1) {
        int t = (threadIdx.x >= off) ? s[threadIdx.x - off] : 0;
        __syncthreads();
        s[threadIdx.x] += t;
        __syncthreads();
    }
    row_ptr[i] = s[threadIdx.x] - v;   // exclusive within block
    if (threadIdx.x == 255) bsum[blockIdx.x] = s[255];
}

// Exclusive scan of bsum[NB] in place, single block of NB threads (NB<=1024).
__global__ void scan2_kernel(int* __restrict__ bsum, int NB) {
    extern __shared__ int s2[];
    int v = (threadIdx.x < NB) ? bsum[threadIdx.x] : 0;
    s2[threadIdx.x] = v;
    __syncthreads();
    for (int off = 1; off < NB; off <<= 1) {
        int t = (threadIdx.x >= off) ? s2[threadIdx.x - off] : 0;
        __syncthreads();
        s2[threadIdx.x] += t;
        __syncthreads();
    }
    if (threadIdx.x < NB) bsum[threadIdx.x] = s2[threadIdx.x] - v;
}

__global__ void scan3_kernel(int* __restrict__ row_ptr, const int* __restrict__ bsum,
                             int N, int E) {
    int i = blockIdx.x * 256 + threadIdx.x;
    row_ptr[i] += bsum[blockIdx.x];
    if (i == 0) row_ptr[N] = E;
}

// Atomic-free CSR fill: position comes from precomputed rank.
__global__ void fill_kernel(const int* __restrict__ src, const int* __restrict__ dst,
                            const int* __restrict__ row_ptr, const int* __restrict__ rank,
                            int* __restrict__ csr_src, int E) {
    int i = blockIdx.x * blockDim.x + threadIdx.x;
    if (i >= E) return;
    csr_src[row_ptr[dst[i]] + rank[i]] = src[i];
}

__global__ void lin16_kernel(const float* __restrict__ x, const float* __restrict__ W,
                             const float* __restrict__ b, float* __restrict__ h, int N) {
    __shared__ float sW[256];
    __shared__ float sb[16];
    sW[threadIdx.x] = W[threadIdx.x];          // blockDim.x == 256
    if (threadIdx.x < 16) sb[threadIdx.x] = b[threadIdx.x];
    __syncthreads();
    int n = blockIdx.x * blockDim.x + threadIdx.x;
    if (n >= N) return;
    const float4* xr = (const float4*)(x + (size_t)n * 16);
    float4 x0 = xr[0], x1 = xr[1], x2 = xr[2], x3 = xr[3];
    float xi[16] = {x0.x, x0.y, x0.z, x0.w, x1.x, x1.y, x1.z, x1.w,
                    x2.x, x2.y, x2.z, x2.w, x3.x, x3.y, x3.z, x3.w};
    float o[16];
#pragma unroll
    for (int j = 0; j < 16; j++) o[j] = sb[j];
#pragma unroll
    for (int k = 0; k < 16; k++) {
        float xv = xi[k];
#pragma unroll
        for (int j = 0; j < 16; j++) o[j] += xv * sW[k * 16 + j];
    }
    float4* hr = (float4*)(h + (size_t)n * 16);
    hr[0] = make_float4(o[0], o[1], o[2], o[3]);
    hr[1] = make_float4(o[4], o[5], o[6], o[7]);
    hr[2] = make_float4(o[8], o[9], o[10], o[11]);
    hr[3] = make_float4(o[12], o[13], o[14], o[15]);
}

// agg[n][g*4..] = (1/max(deg,1)) * sum over CSR neighbors of h[src][g*4..]
template <int C>
__global__ void gather_kernel(const int* __restrict__ row_ptr, const int* __restrict__ csr_src,
                              const float* __restrict__ h, float* __restrict__ agg, int N) {
    constexpr int GP = C / 4;
    int t = blockIdx.x * blockDim.x + threadIdx.x;
    int total = N * GP;
    if (t >= total) return;
    int n = t / GP;
    int g = t - n * GP;
    int beg = row_ptr[n];
    int end = row_ptr[n + 1];
    float4 s = make_float4(0.f, 0.f, 0.f, 0.f);
    for (int j = beg; j < end; ++j) {
        int sn = csr_src[j];
        float4 v = *(const float4*)(h + (size_t)sn * C + g * 4);
        s.x += v.x; s.y += v.y; s.z += v.z; s.w += v.w;
    }
    float inv = 1.0f / fmaxf((float)(end - beg), 1.0f);
    s.x *= inv; s.y *= inv; s.z *= inv; s.w *= inv;
    *(float4*)(agg + (size_t)n * C + g * 4) = s;
}

// Register-blocked GEMM: out = act([h | a] @ [Ws; Wn] + b). 256 threads.
// Thread owns TM interleaved rows (m = ty + TY*r) x TN=4 cols; As m-major.
// ACT: 0 = relu, 1 = sigmoid
template <int CI, int NOUT, int TM, int TN, int ACT>
__global__ __launch_bounds__(256) void gemm_kernel(
    const float* __restrict__ hbuf,   // [N][CI]
    const float* __restrict__ abuf,   // [N][CI]  (already divided by deg)
    const float* __restrict__ Ws,     // [CI][NOUT]
    const float* __restrict__ Wn,     // [CI][NOUT]
    const float* __restrict__ bias,   // [NOUT]
    float* __restrict__ out, int N)
{
    constexpr int K   = 2 * CI;
    constexpr int BK  = (CI < 32) ? CI : 32;   // each chunk entirely in h- or a-half
    constexpr int KQ  = BK / 4;
    constexpr int TX  = NOUT / TN;
    constexpr int TY  = 256 / TX;
    constexpr int BM  = TY * TM;
    constexpr int LDA = BK + 4;                // multiple of 4 -> float4-aligned rows
    __shared__ float As[BM][LDA];
    __shared__ float Bs[BK][NOUT];

    const int tid  = threadIdx.x;
    const int tx   = tid % TX;
    const int ty   = tid / TX;
    const int row0 = blockIdx.x * BM;
    const int j0   = tx * TN;

    float acc[TM][TN];
#pragma unroll
    for (int r = 0; r < TM; r++)
#pragma unroll
        for (int j = 0; j < TN; j++) acc[r][j] = 0.0f;

#pragma unroll 1
    for (int k0 = 0; k0 < K; k0 += BK) {
        const float* Asrc;
        const float* Bsrc;
        int ks;
        if (k0 < CI) { Asrc = hbuf; Bsrc = Ws; ks = k0; }
        else         { Asrc = abuf; Bsrc = Wn; ks = k0 - CI; }

        for (int idx = tid; idx < BM * KQ; idx += 256) {
            int m  = idx / KQ;
            int kq = idx - m * KQ;
            float4 v = *(const float4*)(Asrc + (size_t)(row0 + m) * CI + ks + kq * 4);
            *(float4*)&As[m][kq * 4] = v;
        }
        for (int idx = tid; idx < BK * (NOUT / 4); idx += 256) {
            int kk = idx / (NOUT / 4);
            int jq = idx - kk * (NOUT / 4);
            *(float4*)&Bs[kk][jq * 4] =
                *(const float4*)(Bsrc + (size_t)(ks + kk) * NOUT + jq * 4);
        }
        __syncthreads();

#pragma unroll 8
        for (int k = 0; k < BK; k++) {
            float4 bv = *(const float4*)&Bs[k][j0];
            float a[TM];
#pragma unroll
            for (int r = 0; r < TM; r++) a[r] = As[ty + TY * r][k];
#pragma unroll
            for (int r = 0; r < TM; r++) {
                acc[r][0] += a[r] * bv.x;
                acc[r][1] += a[r] * bv.y;
                acc[r][2] += a[r] * bv.z;
                acc[r][3] += a[r] * bv.w;
            }
        }
        __syncthreads();
    }

    float4 bb = *(const float4*)(bias + j0);
#pragma unroll
    for (int r = 0; r < TM; r++) {
        size_t nrow = (size_t)(row0 + ty + TY * r);
        float4 v;
        v.x = acc[r][0] + bb.x;
        v.y = acc[r][1] + bb.y;
        v.z = acc[r][2] + bb.z;
        v.w = acc[r][3] + bb.w;
        if (ACT == 0) {
            v.x = fmaxf(v.x, 0.0f); v.y = fmaxf(v.y, 0.0f);
            v.z = fmaxf(v.z, 0.0f); v.w = fmaxf(v.w, 0.0f);
        } else {
            v.x = 1.0f / (1.0f + __expf(-v.x));
            v.y = 1.0f / (1.0f + __expf(-v.y));
            v.z = 1.0f / (1.0f + __expf(-v.z));
            v.w = 1.0f / (1.0f + __expf(-v.w));
        }
        *(float4*)(out + nrow * NOUT + j0) = v;
    }
}

extern "C" void kernel_launch(void* const* d_in, const int* in_sizes, int n_in,
                              void* d_out, int out_size, void* d_ws, size_t ws_size,
                              hipStream_t stream) {
    const float* x     = (const float*)d_in[0];
    const int*   ei    = (const int*)d_in[1];
    // d_in[2]: batch (unused)
    const float* W_lin = (const float*)d_in[3];
    const float* b_lin = (const float*)d_in[4];
    const float* Ws3   = (const float*)d_in[5];
    const float* Wn3   = (const float*)d_in[6];
    const float* b3    = (const float*)d_in[7];
    const float* Ws2   = (const float*)d_in[8];
    const float* Wn2   = (const float*)d_in[9];
    const float* b2    = (const float*)d_in[10];
    const float* Ws1   = (const float*)d_in[11];
    const float* Wn1   = (const float*)d_in[12];
    const float* b1    = (const float*)d_in[13];
    float* out = (float*)d_out;

    const int N = in_sizes[0] / 16;
    const int E = in_sizes[1] / 2;
    const int* src = ei;
    const int* dst = ei + E;
    const int NB = (N + 255) / 256;   // scan blocks (512 for N=131072)

    // Workspace (4 B elems). Peak = 76.55 MB (same aliasing as R2-R4, proven fit).
    //   row_ptr : [0, N+1)
    //   cnt     : [N+1, 2N+1)
    //   bsum    : [2N+1, 2N+1+NB)
    //   csr_src : [A, A+E)
    //   regionA (64N floats): h0 [0,16N) agg16 [16N,32N); later h2 [0,64N)
    //   regionB (64N floats): rank [0,E) during CSR build (dead before h3);
    //                         h3 [0,32N) agg32 [32N,64N); later agg64 [0,64N)
    int* wsi = (int*)d_ws;
    int* row_ptr = wsi;
    int* cnt     = wsi + (N + 1);
    int* bsum    = wsi + (2 * N + 1);
    size_t A = (size_t)(2 * N + 1 + NB + 3) & ~(size_t)3;
    int* csr_src = wsi + A;
    size_t P0 = (A + (size_t)E + 3) & ~(size_t)3;
    float* regA = (float*)(wsi + P0);
    float* regB = regA + (size_t)64 * N;

    float* h0    = regA;
    float* agg16 = regA + (size_t)16 * N;
    float* h2    = regA;                      // after h0/agg16 dead
    int*   rank  = (int*)regB;                // CSR-build only (E <= 32N ints)
    float* h3    = regB;
    float* agg32 = regB + (size_t)32 * N;
    float* agg64 = regB;                      // after h3/agg32 dead

    const int BLK = 256;

    // ---- CSR build: hist computes rank; fill is atomic-free ----
    hipMemsetAsync(cnt, 0, (size_t)N * 4, stream);
    hist_rank_kernel<<<(E + BLK - 1) / BLK, BLK, 0, stream>>>(dst, cnt, rank, E);
    scan1_kernel<<<NB, 256, 0, stream>>>(cnt, row_ptr, bsum);
    scan2_kernel<<<1, NB, NB * sizeof(int), stream>>>(bsum, NB);
    scan3_kernel<<<NB, 256, 0, stream>>>(row_ptr, bsum, N, E);
    fill_kernel<<<(E + BLK - 1) / BLK, BLK, 0, stream>>>(src, dst, row_ptr, rank, csr_src, E);

    // ---- h0 = x @ W_lin + b_lin ----
    lin16_kernel<<<(N + BLK - 1) / BLK, BLK, 0, stream>>>(x, W_lin, b_lin, h0, N);

    // ---- block3: 16 -> 32, relu ----  (BM = 128)
    gather_kernel<16><<<((size_t)N * 4 + BLK - 1) / BLK, BLK, 0, stream>>>(row_ptr, csr_src, h0, agg16, N);
    gemm_kernel<16, 32, 4, 4, 0><<<N / 128, 256, 0, stream>>>(h0, agg16, Ws3, Wn3, b3, h3, N);

    // ---- block2: 32 -> 64, relu ----  (BM = 128)
    gather_kernel<32><<<((size_t)N * 8 + BLK - 1) / BLK, BLK, 0, stream>>>(row_ptr, csr_src, h3, agg32, N);
    gemm_kernel<32, 64, 8, 4, 0><<<N / 128, 256, 0, stream>>>(h3, agg32, Ws2, Wn2, b2, h2, N);

    // ---- block1: 64 -> 128, sigmoid -> d_out ----  (BM = 64)
    gather_kernel<64><<<((size_t)N * 16 + BLK - 1) / BLK, BLK, 0, stream>>>(row_ptr, csr_src, h2, agg64, N);
    gemm_kernel<64, 128, 8, 4, 1><<<N / 64, 256, 0, stream>>>(h2, agg64, Ws1, Wn1, b1, out, N);
}

// Round 6
// 538.916 us; speedup vs baseline: 6.2332x; 1.0168x over previous
//
#include <hip/hip_runtime.h>
#include <cmath>

// ---------------------------------------------------------------------------
// Decoder_1898375544952: STGCN decoder (CSR gather + register-blocked GEMM)
//   h0 = x @ W_lin + b_lin                         [N,16]
//   h3 = relu(h0 @ Ws3 + mean_agg(h0) @ Wn3 + b3)  [N,32]
//   h2 = relu(h3 @ Ws2 + mean_agg(h3) @ Wn2 + b2)  [N,64]
//   out= sigm(h2 @ Ws1 + mean_agg(h2) @ Wn1 + b1)  [N,128]
//
// R1: fp32 atomic scatter = 2 GB HBM write-through -> CSR gather (4.7x).
// R2: combine kernels LDS-BW bound -> register-blocked GEMM.
// R3: over-unrolled GEMM spilled (VGPR=256) -> unroll-1 chunks, TMx4 tiles.
// R4: fill = atomic+dependent-random-store -> rank from hist atomicAdd.
// R5: gather latency-bound (VALUBusy 10%, 1 outstanding 16B load/lane) ->
// R6: 8-way unrolled neighbor loop, 4 independent accumulators: 8 loads in
//     flight per lane before any consuming add.
// ---------------------------------------------------------------------------

__global__ void hist_rank_kernel(const int* __restrict__ dst, int* __restrict__ cnt,
                                 int* __restrict__ rank, int E) {
    int i = blockIdx.x * blockDim.x + threadIdx.x;
    if (i >= E) return;
    rank[i] = atomicAdd(&cnt[dst[i]], 1);
}

// Block-level exclusive scan of cnt -> row_ptr (partial), block sums -> bsum.
// Requires N % 256 == 0.
__global__ void scan1_kernel(const int* __restrict__ cnt, int* __restrict__ row_ptr,
                             int* __restrict__ bsum) {
    __shared__ int s[256];
    int i = blockIdx.x * 256 + threadIdx.x;
    int v = cnt[i];
    s[threadIdx.x] = v;
    __syncthreads();
    for (int off = 1; off < 256; off <<= 1) {
        int t = (threadIdx.x >= off) ? s[threadIdx.x - off] : 0;
        __syncthreads();
        s[threadIdx.x] += t;
        __syncthreads();
    }
    row_ptr[i] = s[threadIdx.x] - v;   // exclusive within block
    if (threadIdx.x == 255) bsum[blockIdx.x] = s[255];
}

// Exclusive scan of bsum[NB] in place, single block of NB threads (NB<=1024).
__global__ void scan2_kernel(int* __restrict__ bsum, int NB) {
    extern __shared__ int s2[];
    int v = (threadIdx.x < NB) ? bsum[threadIdx.x] : 0;
    s2[threadIdx.x] = v;
    __syncthreads();
    for (int off = 1; off < NB; off <<= 1) {
        int t = (threadIdx.x >= off) ? s2[threadIdx.x - off] : 0;
        __syncthreads();
        s2[threadIdx.x] += t;
        __syncthreads();
    }
    if (threadIdx.x < NB) bsum[threadIdx.x] = s2[threadIdx.x] - v;
}

__global__ void scan3_kernel(int* __restrict__ row_ptr, const int* __restrict__ bsum,
                             int N, int E) {
    int i = blockIdx.x * 256 + threadIdx.x;
    row_ptr[i] += bsum[blockIdx.x];
    if (i == 0) row_ptr[N] = E;
}

// Atomic-free CSR fill: position comes from precomputed rank.
__global__ void fill_kernel(const int* __restrict__ src, const int* __restrict__ dst,
                            const int* __restrict__ row_ptr, const int* __restrict__ rank,
                            int* __restrict__ csr_src, int E) {
    int i = blockIdx.x * blockDim.x + threadIdx.x;
    if (i >= E) return;
    csr_src[row_ptr[dst[i]] + rank[i]] = src[i];
}

__global__ void lin16_kernel(const float* __restrict__ x, const float* __restrict__ W,
                             const float* __restrict__ b, float* __restrict__ h, int N) {
    __shared__ float sW[256];
    __shared__ float sb[16];
    sW[threadIdx.x] = W[threadIdx.x];          // blockDim.x == 256
    if (threadIdx.x < 16) sb[threadIdx.x] = b[threadIdx.x];
    __syncthreads();
    int n = blockIdx.x * blockDim.x + threadIdx.x;
    if (n >= N) return;
    const float4* xr = (const float4*)(x + (size_t)n * 16);
    float4 x0 = xr[0], x1 = xr[1], x2 = xr[2], x3 = xr[3];
    float xi[16] = {x0.x, x0.y, x0.z, x0.w, x1.x, x1.y, x1.z, x1.w,
                    x2.x, x2.y, x2.z, x2.w, x3.x, x3.y, x3.z, x3.w};
    float o[16];
#pragma unroll
    for (int j = 0; j < 16; j++) o[j] = sb[j];
#pragma unroll
    for (int k = 0; k < 16; k++) {
        float xv = xi[k];
#pragma unroll
        for (int j = 0; j < 16; j++) o[j] += xv * sW[k * 16 + j];
    }
    float4* hr = (float4*)(h + (size_t)n * 16);
    hr[0] = make_float4(o[0], o[1], o[2], o[3]);
    hr[1] = make_float4(o[4], o[5], o[6], o[7]);
    hr[2] = make_float4(o[8], o[9], o[10], o[11]);
    hr[3] = make_float4(o[12], o[13], o[14], o[15]);
}

// agg[n][g*4..] = (1/max(deg,1)) * sum over CSR neighbors of h[src][g*4..]
// 8-way unrolled neighbor loop: 8 independent loads in flight per lane.
template <int C>
__global__ void gather_kernel(const int* __restrict__ row_ptr, const int* __restrict__ csr_src,
                              const float* __restrict__ h, float* __restrict__ agg, int N) {
    constexpr int GP = C / 4;
    int t = blockIdx.x * blockDim.x + threadIdx.x;
    int total = N * GP;
    if (t >= total) return;
    int n = t / GP;
    int g = t - n * GP;
    const int beg = row_ptr[n];
    const int end = row_ptr[n + 1];
    const size_t goff = (size_t)g * 4;

    float4 s0 = make_float4(0.f, 0.f, 0.f, 0.f);
    float4 s1 = s0, s2 = s0, s3 = s0;

    int j = beg;
    for (; j + 8 <= end; j += 8) {
        int i0 = csr_src[j + 0], i1 = csr_src[j + 1], i2 = csr_src[j + 2], i3 = csr_src[j + 3];
        int i4 = csr_src[j + 4], i5 = csr_src[j + 5], i6 = csr_src[j + 6], i7 = csr_src[j + 7];
        float4 v0 = *(const float4*)(h + (size_t)i0 * C + goff);
        float4 v1 = *(const float4*)(h + (size_t)i1 * C + goff);
        float4 v2 = *(const float4*)(h + (size_t)i2 * C + goff);
        float4 v3 = *(const float4*)(h + (size_t)i3 * C + goff);
        float4 v4 = *(const float4*)(h + (size_t)i4 * C + goff);
        float4 v5 = *(const float4*)(h + (size_t)i5 * C + goff);
        float4 v6 = *(const float4*)(h + (size_t)i6 * C + goff);
        float4 v7 = *(const float4*)(h + (size_t)i7 * C + goff);
        s0.x += v0.x; s0.y += v0.y; s0.z += v0.z; s0.w += v0.w;
        s1.x += v1.x; s1.y += v1.y; s1.z += v1.z; s1.w += v1.w;
        s2.x += v2.x; s2.y += v2.y; s2.z += v2.z; s2.w += v2.w;
        s3.x += v3.x; s3.y += v3.y; s3.z += v3.z; s3.w += v3.w;
        s0.x += v4.x; s0.y += v4.y; s0.z += v4.z; s0.w += v4.w;
        s1.x += v5.x; s1.y += v5.y; s1.z += v5.z; s1.w += v5.w;
        s2.x += v6.x; s2.y += v6.y; s2.z += v6.z; s2.w += v6.w;
        s3.x += v7.x; s3.y += v7.y; s3.z += v7.z; s3.w += v7.w;
    }
    for (; j + 2 <= end; j += 2) {
        int i0 = csr_src[j + 0], i1 = csr_src[j + 1];
        float4 v0 = *(const float4*)(h + (size_t)i0 * C + goff);
        float4 v1 = *(const float4*)(h + (size_t)i1 * C + goff);
        s0.x += v0.x; s0.y += v0.y; s0.z += v0.z; s0.w += v0.w;
        s1.x += v1.x; s1.y += v1.y; s1.z += v1.z; s1.w += v1.w;
    }
    if (j < end) {
        int i0 = csr_src[j];
        float4 v0 = *(const float4*)(h + (size_t)i0 * C + goff);
        s2.x += v0.x; s2.y += v0.y; s2.z += v0.z; s2.w += v0.w;
    }

    float4 s;
    s.x = (s0.x + s1.x) + (s2.x + s3.x);
    s.y = (s0.y + s1.y) + (s2.y + s3.y);
    s.z = (s0.z + s1.z) + (s2.z + s3.z);
    s.w = (s0.w + s1.w) + (s2.w + s3.w);
    float inv = 1.0f / fmaxf((float)(end - beg), 1.0f);
    s.x *= inv; s.y *= inv; s.z *= inv; s.w *= inv;
    *(float4*)(agg + (size_t)n * C + goff) = s;
}

// Register-blocked GEMM: out = act([h | a] @ [Ws; Wn] + b). 256 threads.
// Thread owns TM interleaved rows (m = ty + TY*r) x TN=4 cols; As m-major.
// ACT: 0 = relu, 1 = sigmoid
template <int CI, int NOUT, int TM, int TN, int ACT>
__global__ __launch_bounds__(256) void gemm_kernel(
    const float* __restrict__ hbuf,   // [N][CI]
    const float* __restrict__ abuf,   // [N][CI]  (already divided by deg)
    const float* __restrict__ Ws,     // [CI][NOUT]
    const float* __restrict__ Wn,     // [CI][NOUT]
    const float* __restrict__ bias,   // [NOUT]
    float* __restrict__ out, int N)
{
    constexpr int K   = 2 * CI;
    constexpr int BK  = (CI < 32) ? CI : 32;   // each chunk entirely in h- or a-half
    constexpr int KQ  = BK / 4;
    constexpr int TX  = NOUT / TN;
    constexpr int TY  = 256 / TX;
    constexpr int BM  = TY * TM;
    constexpr int LDA = BK + 4;                // multiple of 4 -> float4-aligned rows
    __shared__ float As[BM][LDA];
    __shared__ float Bs[BK][NOUT];

    const int tid  = threadIdx.x;
    const int tx   = tid % TX;
    const int ty   = tid / TX;
    const int row0 = blockIdx.x * BM;
    const int j0   = tx * TN;

    float acc[TM][TN];
#pragma unroll
    for (int r = 0; r < TM; r++)
#pragma unroll
        for (int j = 0; j < TN; j++) acc[r][j] = 0.0f;

#pragma unroll 1
    for (int k0 = 0; k0 < K; k0 += BK) {
        const float* Asrc;
        const float* Bsrc;
        int ks;
        if (k0 < CI) { Asrc = hbuf; Bsrc = Ws; ks = k0; }
        else         { Asrc = abuf; Bsrc = Wn; ks = k0 - CI; }

        for (int idx = tid; idx < BM * KQ; idx += 256) {
            int m  = idx / KQ;
            int kq = idx - m * KQ;
            float4 v = *(const float4*)(Asrc + (size_t)(row0 + m) * CI + ks + kq * 4);
            *(float4*)&As[m][kq * 4] = v;
        }
        for (int idx = tid; idx < BK * (NOUT / 4); idx += 256) {
            int kk = idx / (NOUT / 4);
            int jq = idx - kk * (NOUT / 4);
            *(float4*)&Bs[kk][jq * 4] =
                *(const float4*)(Bsrc + (size_t)(ks + kk) * NOUT + jq * 4);
        }
        __syncthreads();

#pragma unroll 8
        for (int k = 0; k < BK; k++) {
            float4 bv = *(const float4*)&Bs[k][j0];
            float a[TM];
#pragma unroll
            for (int r = 0; r < TM; r++) a[r] = As[ty + TY * r][k];
#pragma unroll
            for (int r = 0; r < TM; r++) {
                acc[r][0] += a[r] * bv.x;
                acc[r][1] += a[r] * bv.y;
                acc[r][2] += a[r] * bv.z;
                acc[r][3] += a[r] * bv.w;
            }
        }
        __syncthreads();
    }

    float4 bb = *(const float4*)(bias + j0);
#pragma unroll
    for (int r = 0; r < TM; r++) {
        size_t nrow = (size_t)(row0 + ty + TY * r);
        float4 v;
        v.x = acc[r][0] + bb.x;
        v.y = acc[r][1] + bb.y;
        v.z = acc[r][2] + bb.z;
        v.w = acc[r][3] + bb.w;
        if (ACT == 0) {
            v.x = fmaxf(v.x, 0.0f); v.y = fmaxf(v.y, 0.0f);
            v.z = fmaxf(v.z, 0.0f); v.w = fmaxf(v.w, 0.0f);
        } else {
            v.x = 1.0f / (1.0f + __expf(-v.x));
            v.y = 1.0f / (1.0f + __expf(-v.y));
            v.z = 1.0f / (1.0f + __expf(-v.z));
            v.w = 1.0f / (1.0f + __expf(-v.w));
        }
        *(float4*)(out + nrow * NOUT + j0) = v;
    }
}

extern "C" void kernel_launch(void* const* d_in, const int* in_sizes, int n_in,
                              void* d_out, int out_size, void* d_ws, size_t ws_size,
                              hipStream_t stream) {
    const float* x     = (const float*)d_in[0];
    const int*   ei    = (const int*)d_in[1];
    // d_in[2]: batch (unused)
    const float* W_lin = (const float*)d_in[3];
    const float* b_lin = (const float*)d_in[4];
    const float* Ws3   = (const float*)d_in[5];
    const float* Wn3   = (const float*)d_in[6];
    const float* b3    = (const float*)d_in[7];
    const float* Ws2   = (const float*)d_in[8];
    const float* Wn2   = (const float*)d_in[9];
    const float* b2    = (const float*)d_in[10];
    const float* Ws1   = (const float*)d_in[11];
    const float* Wn1   = (const float*)d_in[12];
    const float* b1    = (const float*)d_in[13];
    float* out = (float*)d_out;

    const int N = in_sizes[0] / 16;
    const int E = in_sizes[1] / 2;
    const int* src = ei;
    const int* dst = ei + E;
    const int NB = (N + 255) / 256;   // scan blocks (512 for N=131072)

    // Workspace (4 B elems). Peak = 76.55 MB (same aliasing as R2-R5, proven fit).
    //   row_ptr : [0, N+1)
    //   cnt     : [N+1, 2N+1)
    //   bsum    : [2N+1, 2N+1+NB)
    //   csr_src : [A, A+E)
    //   regionA (64N floats): h0 [0,16N) agg16 [16N,32N); later h2 [0,64N)
    //   regionB (64N floats): rank [0,E) during CSR build (dead before h3);
    //                         h3 [0,32N) agg32 [32N,64N); later agg64 [0,64N)
    int* wsi = (int*)d_ws;
    int* row_ptr = wsi;
    int* cnt     = wsi + (N + 1);
    int* bsum    = wsi + (2 * N + 1);
    size_t A = (size_t)(2 * N + 1 + NB + 3) & ~(size_t)3;
    int* csr_src = wsi + A;
    size_t P0 = (A + (size_t)E + 3) & ~(size_t)3;
    float* regA = (float*)(wsi + P0);
    float* regB = regA + (size_t)64 * N;

    float* h0    = regA;
    float* agg16 = regA + (size_t)16 * N;
    float* h2    = regA;                      // after h0/agg16 dead
    int*   rank  = (int*)regB;                // CSR-build only (E <= 32N ints)
    float* h3    = regB;
    float* agg32 = regB + (size_t)32 * N;
    float* agg64 = regB;                      // after h3/agg32 dead

    const int BLK = 256;

    // ---- CSR build: hist computes rank; fill is atomic-free ----
    hipMemsetAsync(cnt, 0, (size_t)N * 4, stream);
    hist_rank_kernel<<<(E + BLK - 1) / BLK, BLK, 0, stream>>>(dst, cnt, rank, E);
    scan1_kernel<<<NB, 256, 0, stream>>>(cnt, row_ptr, bsum);
    scan2_kernel<<<1, NB, NB * sizeof(int), stream>>>(bsum, NB);
    scan3_kernel<<<NB, 256, 0, stream>>>(row_ptr, bsum, N, E);
    fill_kernel<<<(E + BLK - 1) / BLK, BLK, 0, stream>>>(src, dst, row_ptr, rank, csr_src, E);

    // ---- h0 = x @ W_lin + b_lin ----
    lin16_kernel<<<(N + BLK - 1) / BLK, BLK, 0, stream>>>(x, W_lin, b_lin, h0, N);

    // ---- block3: 16 -> 32, relu ----  (BM = 128)
    gather_kernel<16><<<((size_t)N * 4 + BLK - 1) / BLK, BLK, 0, stream>>>(row_ptr, csr_src, h0, agg16, N);
    gemm_kernel<16, 32, 4, 4, 0><<<N / 128, 256, 0, stream>>>(h0, agg16, Ws3, Wn3, b3, h3, N);

    // ---- block2: 32 -> 64, relu ----  (BM = 128)
    gather_kernel<32><<<((size_t)N * 8 + BLK - 1) / BLK, BLK, 0, stream>>>(row_ptr, csr_src, h3, agg32, N);
    gemm_kernel<32, 64, 8, 4, 0><<<N / 128, 256, 0, stream>>>(h3, agg32, Ws2, Wn2, b2, h2, N);

    // ---- block1: 64 -> 128, sigmoid -> d_out ----  (BM = 64)
    gather_kernel<64><<<((size_t)N * 16 + BLK - 1) / BLK, BLK, 0, stream>>>(row_ptr, csr_src, h2, agg64, N);
    gemm_kernel<64, 128, 8, 4, 1><<<N / 64, 256, 0, stream>>>(h2, agg64, Ws1, Wn1, b1, out, N);
}